// Round 1
// baseline (200.564 us; speedup 1.0000x reference)
//
#include <hip/hip_runtime.h>

#define Nn 2048
#define FIN 512
#define FO 64
#define NEG_BIG -9.0e15f
#define CH 64
#define LST 66   // padded LDS row stride (floats): stride 66 -> b64 reads hit all 32 banks

// ---------------- K1: h = x @ W ----------------
// grid 128 x 256. Each wave computes 4 rows x 64 cols; x loads are wave-uniform
// (readfirstlane-forced) -> scalar loads; W loads coalesced (lane = output col).
__global__ __launch_bounds__(256) void gat_xw(const float* __restrict__ x,
                                              const float* __restrict__ W,
                                              float* __restrict__ h) {
    const int wave = threadIdx.x >> 6;
    const int lane = threadIdx.x & 63;
    int ib = (blockIdx.x * 4 + wave) * 4;
    ib = __builtin_amdgcn_readfirstlane(ib);
    const float* xr0 = x + (size_t)ib * FIN;
    float acc[4] = {0.f, 0.f, 0.f, 0.f};
    for (int k = 0; k < FIN; k += 4) {
        float w0 = W[(k + 0) * FO + lane];
        float w1 = W[(k + 1) * FO + lane];
        float w2 = W[(k + 2) * FO + lane];
        float w3 = W[(k + 3) * FO + lane];
#pragma unroll
        for (int r = 0; r < 4; r++) {
            const float* xr = xr0 + r * FIN + k;
            acc[r] = fmaf(xr[0], w0, acc[r]);
            acc[r] = fmaf(xr[1], w1, acc[r]);
            acc[r] = fmaf(xr[2], w2, acc[r]);
            acc[r] = fmaf(xr[3], w3, acc[r]);
        }
    }
#pragma unroll
    for (int r = 0; r < 4; r++)
        h[(size_t)(ib + r) * FO + lane] = acc[r];
}

// ---------------- K2: fused scores + masked online softmax + PV + relu ----------------
// grid 512 x 256. One wave per row i (4 rows per block). Lane <-> j within a
// 64-j chunk. h-chunk staged once per block into LDS (stride-66 pad), read into
// 64 VGPRs per lane, reused for e-phase AND PV. h_i & a broadcast from LDS.
__global__ __launch_bounds__(256) void gat_attn(const float* __restrict__ h,
                                                const int* __restrict__ adj,
                                                const float* __restrict__ a,
                                                float* __restrict__ out) {
    __shared__ float hj[CH * LST];       // 16896 B staged h chunk (reused for final reduce)
    __shared__ float hia[4 * FO * 2];    // per-wave interleaved {h_i[f], a[f]}
    const int tid = threadIdx.x;
    const int wave = tid >> 6;
    const int lane = tid & 63;
    const int row = blockIdx.x * 4 + wave;

    hia[wave * (FO * 2) + lane * 2]     = h[(size_t)row * FO + lane];
    hia[wave * (FO * 2) + lane * 2 + 1] = a[lane];

    float m = -__builtin_inff();
    float l = 0.f;
    float op[FO];
#pragma unroll
    for (int f = 0; f < FO; f++) op[f] = 0.f;

    const int* adjrow = adj + (size_t)row * Nn;

    for (int j0 = 0; j0 < Nn; j0 += CH) {
        __syncthreads();   // previous chunk's consumers done (also orders hia on iter 0)
        // stage chunk j0..j0+63 (64 rows x 64 f) -> hj with stride-66 padding.
        // global side perfectly coalesced float4; LDS writes b64 (8B-aligned).
#pragma unroll
        for (int u = 0; u < 4; u++) {
            int g4 = u * 256 + tid;                 // float4 index within chunk [0,1024)
            const float4 v = *(const float4*)(h + (size_t)j0 * FO + (size_t)g4 * 4);
            float* dst = &hj[(g4 >> 4) * LST + (g4 & 15) * 4];
            ((float2*)dst)[0] = make_float2(v.x, v.y);
            *(float2*)(dst + 2) = make_float2(v.z, v.w);
        }
        __syncthreads();

        // h_j for this lane's j into registers (32 x b64, banks fully spread)
        float2 hjv[32];
#pragma unroll
        for (int q = 0; q < 32; q++)
            hjv[q] = *(const float2*)&hj[lane * LST + q * 2];

        // e = sum_f a_f * |h_i[f] - h_j[f]|   (abs folds into VOP3 modifier)
        float e = 0.f;
#pragma unroll
        for (int q = 0; q < 32; q++) {
            float4 c = *(const float4*)&hia[wave * (FO * 2) + q * 4];  // {hi,a,hi,a} broadcast
            e = fmaf(fabsf(hjv[q].x - c.x), c.y, e);
            e = fmaf(fabsf(hjv[q].y - c.z), c.w, e);
        }

        const int av = adjrow[j0 + lane];
        const float score = (av > 0) ? fmaxf(e, 0.f) : NEG_BIG;

        // chunk max (butterfly over 64 lanes)
        float cm = score;
#pragma unroll
        for (int s = 32; s >= 1; s >>= 1)
            cm = fmaxf(cm, __shfl_xor(cm, s, 64));

        const float mn = fmaxf(m, cm);
        const float p = __expf(score - mn);   // masked: exp(-9e15 - mn) == 0 exactly

        float cs = p;
#pragma unroll
        for (int s = 32; s >= 1; s >>= 1)
            cs += __shfl_xor(cs, s, 64);

        if (mn > m) {                          // wave-uniform, rare after warm-up
            const float alpha = __expf(m - mn);   // first chunk: exp(-inf)=0, zeroes stale state
            l *= alpha;
#pragma unroll
            for (int f = 0; f < FO; f++) op[f] *= alpha;
            m = mn;
        }
        l += cs;

        // PV: reuse hjv registers — no second LDS read
#pragma unroll
        for (int q = 0; q < 32; q++) {
            op[2 * q]     = fmaf(p, hjv[q].x, op[2 * q]);
            op[2 * q + 1] = fmaf(p, hjv[q].y, op[2 * q + 1]);
        }
    }

    // reduce op[] across the 64 lanes of the wave.
    // Step 1: fold lanes 16/32 apart -> every lane holds its 4-lane-group partial.
#pragma unroll
    for (int f = 0; f < FO; f++) {
        op[f] += __shfl_xor(op[f], 16, 64);
        op[f] += __shfl_xor(op[f], 32, 64);
    }
    __syncthreads();   // all waves done reading hj; reuse it as reduction scratch
    float* red = &hj[wave * (16 * 65)];      // 4 x 1040 floats <= 4224
    if (lane < 16) {
#pragma unroll
        for (int f = 0; f < FO; f++)
            red[lane * 65 + f] = op[f];      // stride 65: conflict-free
    }
    float tot = 0.f;
#pragma unroll
    for (int g = 0; g < 16; g++)
        tot += red[g * 65 + lane];           // (g+lane)%32: 2-way max -> free
    out[(size_t)row * FO + lane] = fmaxf(tot / l, 0.f);
}

extern "C" void kernel_launch(void* const* d_in, const int* in_sizes, int n_in,
                              void* d_out, int out_size, void* d_ws, size_t ws_size,
                              hipStream_t stream) {
    const float* x   = (const float*)d_in[0];
    const int*   adj = (const int*)d_in[1];
    const float* W   = (const float*)d_in[2];
    const float* a   = (const float*)d_in[3];
    float* out = (float*)d_out;
    float* h   = (float*)d_ws;   // 2048*64*4 = 512 KB scratch

    gat_xw<<<dim3(128), dim3(256), 0, stream>>>(x, W, h);
    gat_attn<<<dim3(512), dim3(256), 0, stream>>>(h, adj, a, out);
}

// Round 2
// 143.121 us; speedup vs baseline: 1.4014x; 1.4014x over previous
//
#include <hip/hip_runtime.h>

#define Nn 2048
#define FIN 512
#define FO 64
#define SHIFT 20.0f
#define NSEG 4
#define SEGJ (Nn / NSEG)   // 512 j per segment
#define CH 64
#define LST 66             // padded LDS row stride (floats)
#define PSTRIDE 68         // partial row: 64 op + l + pad (16B-aligned)

// ---------------- K1: h = x @ W ----------------
// Block = 4 waves = 2 rows x 2 k-halves. Grid 1024 -> 4096 waves = 16/CU.
// x loads wave-uniform (s_load); W loads coalesced (lane = out col), 16 in flight.
__global__ __launch_bounds__(256) void gat_xw(const float* __restrict__ x,
                                              const float* __restrict__ W,
                                              float* __restrict__ h) {
    __shared__ float part[2][2][FO];
    const int wave = threadIdx.x >> 6;
    const int lane = threadIdx.x & 63;
    const int rs = wave >> 1;      // row sub-index 0/1
    const int kh = wave & 1;       // k half 0/1
    int row = blockIdx.x * 2 + rs;
    row = __builtin_amdgcn_readfirstlane(row);
    const float* xr = x + (size_t)row * FIN + kh * (FIN / 2);
    const float* Wp = W + (size_t)kh * (FIN / 2) * FO;
    float acc = 0.f;
#pragma unroll 2
    for (int k = 0; k < FIN / 2; k += 8) {
        float4 xa = *(const float4*)(xr + k);
        float4 xb = *(const float4*)(xr + k + 4);
        acc = fmaf(xa.x, Wp[(k + 0) * FO + lane], acc);
        acc = fmaf(xa.y, Wp[(k + 1) * FO + lane], acc);
        acc = fmaf(xa.z, Wp[(k + 2) * FO + lane], acc);
        acc = fmaf(xa.w, Wp[(k + 3) * FO + lane], acc);
        acc = fmaf(xb.x, Wp[(k + 4) * FO + lane], acc);
        acc = fmaf(xb.y, Wp[(k + 5) * FO + lane], acc);
        acc = fmaf(xb.z, Wp[(k + 6) * FO + lane], acc);
        acc = fmaf(xb.w, Wp[(k + 7) * FO + lane], acc);
    }
    part[rs][kh][lane] = acc;
    __syncthreads();
    if (threadIdx.x < 128) {
        const int r2 = threadIdx.x >> 6;
        const int l2 = threadIdx.x & 63;
        h[((size_t)blockIdx.x * 2 + r2) * FO + l2] = part[r2][0][l2] + part[r2][1][l2];
    }
}

// ---------------- K2: scores + fixed-shift masked softmax partials + PV ----------------
// One wave per (row, j-segment). Block = 4 waves = 4 rows x same segment (shared
// LDS chunk staging). Grid 2048 -> 8192 waves = 32/CU grid-side (~24 after VGPR).
// NO in-loop shuffles / branches: p = adj ? exp(relu(e)-SHIFT) : 0 is exact
// (masked lanes contribute exactly 0; exp(relu(e)-20) cannot overflow for any
// plausible e; softmax ratios are shift-invariant so result matches reference).
__global__ __launch_bounds__(256) void gat_attn(const float* __restrict__ h,
                                                const int* __restrict__ adj,
                                                const float* __restrict__ a,
                                                float* __restrict__ pws) {
    __shared__ float hj[CH * LST];       // 16.9 KB staged chunk; reused as epilogue scratch
    __shared__ float hia[4 * FO * 2];    // per-wave interleaved {h_i[f], a[f]}
    const int tid = threadIdx.x;
    const int wave = tid >> 6;
    const int lane = tid & 63;
    const int seg = blockIdx.x & (NSEG - 1);
    const int row = (blockIdx.x >> 2) * 4 + wave;

    hia[wave * (FO * 2) + lane * 2]     = h[(size_t)row * FO + lane];
    hia[wave * (FO * 2) + lane * 2 + 1] = a[lane];

    float l = 0.f;
    float2 op2[32];
#pragma unroll
    for (int q = 0; q < 32; q++) op2[q] = make_float2(0.f, 0.f);

    const int* adjrow = adj + (size_t)row * Nn + seg * SEGJ;
    const float* hseg = h + (size_t)seg * SEGJ * FO;

    for (int j0 = 0; j0 < SEGJ; j0 += CH) {
        __syncthreads();   // prev chunk consumed (also orders hia on iter 0)
#pragma unroll
        for (int u = 0; u < 4; u++) {
            const int g4 = u * 256 + tid;                 // float4 idx in chunk [0,1024)
            const float4 v = *(const float4*)(hseg + (size_t)j0 * FO + (size_t)g4 * 4);
            float* dst = &hj[(g4 >> 4) * LST + (g4 & 15) * 4];
            ((float2*)dst)[0] = make_float2(v.x, v.y);
            *(float2*)(dst + 2) = make_float2(v.z, v.w);
        }
        __syncthreads();

        const int av = adjrow[j0 + lane];     // issued early, consumed ~200 instrs later

        float2 hjv[32];
#pragma unroll
        for (int q = 0; q < 32; q++)
            hjv[q] = *(const float2*)&hj[lane * LST + q * 2];

        float e = 0.f;
#pragma unroll
        for (int q = 0; q < 32; q++) {
            const float4 c = *(const float4*)&hia[wave * (FO * 2) + q * 4]; // {hi,a,hi,a} full-bcast
            e = fmaf(fabsf(hjv[q].x - c.x), c.y, e);
            e = fmaf(fabsf(hjv[q].y - c.z), c.w, e);
        }

        const float pe = __expf(fmaxf(e, 0.f) - SHIFT);
        const float p = (av > 0) ? pe : 0.f;
        l += p;

#pragma unroll
        for (int q = 0; q < 32; q++) {
            op2[q].x = fmaf(p, hjv[q].x, op2[q].x);
            op2[q].y = fmaf(p, hjv[q].y, op2[q].y);
        }
    }

    // epilogue (once per wave): reduce l over 64 lanes, op over 4-lane orbits
#pragma unroll
    for (int s = 32; s >= 1; s >>= 1) l += __shfl_xor(l, s, 64);
#pragma unroll
    for (int q = 0; q < 32; q++) {
        op2[q].x += __shfl_xor(op2[q].x, 16, 64);
        op2[q].x += __shfl_xor(op2[q].x, 32, 64);
        op2[q].y += __shfl_xor(op2[q].y, 16, 64);
        op2[q].y += __shfl_xor(op2[q].y, 32, 64);
    }
    __syncthreads();                          // all waves done with hj chunk data
    float* red = &hj[wave * (16 * 65)];       // 4 x 1040 floats <= 4224
    if (lane < 16) {
#pragma unroll
        for (int q = 0; q < 32; q++) {
            red[lane * 65 + 2 * q]     = op2[q].x;   // stride 65: conflict-free
            red[lane * 65 + 2 * q + 1] = op2[q].y;
        }
    }
    float tot = 0.f;
#pragma unroll
    for (int g = 0; g < 16; g++)
        tot += red[g * 65 + lane];            // 2-way max -> free
    float* prow = pws + ((size_t)seg * Nn + row) * PSTRIDE;
    prow[lane] = tot;
    if (lane == 0) prow[FO] = l;
}

// ---------------- K3: merge segment partials ----------------
__global__ __launch_bounds__(256) void gat_merge(const float* __restrict__ pws,
                                                 float* __restrict__ out) {
    const int t = blockIdx.x * 256 + threadIdx.x;   // 0..131071
    const int row = t >> 6;
    const int f = t & 63;
    float o = 0.f, l = 0.f;
#pragma unroll
    for (int s = 0; s < NSEG; s++) {
        const float* pr = pws + ((size_t)s * Nn + row) * PSTRIDE;
        o += pr[f];        // coalesced
        l += pr[FO];       // same-address within row: broadcast via cache
    }
    out[t] = fmaxf(o / l, 0.f);
}

extern "C" void kernel_launch(void* const* d_in, const int* in_sizes, int n_in,
                              void* d_out, int out_size, void* d_ws, size_t ws_size,
                              hipStream_t stream) {
    const float* x   = (const float*)d_in[0];
    const int*   adj = (const int*)d_in[1];
    const float* W   = (const float*)d_in[2];
    const float* a   = (const float*)d_in[3];
    float* out = (float*)d_out;
    float* h   = (float*)d_ws;                       // 2048*64 floats = 512 KB
    float* pws = (float*)d_ws + (size_t)Nn * FO;     // NSEG*2048*68 floats = 2.13 MB

    gat_xw<<<dim3(1024), dim3(256), 0, stream>>>(x, W, h);
    gat_attn<<<dim3(512 * NSEG), dim3(256), 0, stream>>>(h, adj, a, pws);
    gat_merge<<<dim3(512), dim3(256), 0, stream>>>(pws, out);
}

// Round 4
// 136.237 us; speedup vs baseline: 1.4722x; 1.0505x over previous
//
#include <hip/hip_runtime.h>

#define Nn 2048
#define FIN 512
#define FO 64
#define SHIFT 20.0f
#define NJT 16
#define JR (Nn / NJT)   // 128 j per tile -> 2 chunks of 64
#define LS 66           // LDS row stride: even (8B-aligned float2 rows), 4-way worst bank aliasing
#define PTS 68          // pT row stride: 68*4B = 272B -> 16B-aligned float4 rows

// ---------------- K0: zero the accumulators (osum 131072 + lsum 2048 floats, contiguous) ----------------
__global__ __launch_bounds__(256) void gat_zero(float* __restrict__ z) {
    z[blockIdx.x * 256 + threadIdx.x] = 0.f;   // grid 520 * 256 == 133120 exactly
}

// ---------------- K1: h = x @ W  (proven round-2 version) ----------------
__global__ __launch_bounds__(256) void gat_xw(const float* __restrict__ x,
                                              const float* __restrict__ W,
                                              float* __restrict__ h) {
    __shared__ float part[2][2][FO];
    const int wave = threadIdx.x >> 6;
    const int lane = threadIdx.x & 63;
    const int rs = wave >> 1;
    const int kh = wave & 1;
    int row = blockIdx.x * 2 + rs;
    row = __builtin_amdgcn_readfirstlane(row);
    const float* xr = x + (size_t)row * FIN + kh * (FIN / 2);
    const float* Wp = W + (size_t)kh * (FIN / 2) * FO;
    float acc = 0.f;
#pragma unroll 2
    for (int k = 0; k < FIN / 2; k += 8) {
        float4 xa = *(const float4*)(xr + k);
        float4 xb = *(const float4*)(xr + k + 4);
        acc = fmaf(xa.x, Wp[(k + 0) * FO + lane], acc);
        acc = fmaf(xa.y, Wp[(k + 1) * FO + lane], acc);
        acc = fmaf(xa.z, Wp[(k + 2) * FO + lane], acc);
        acc = fmaf(xa.w, Wp[(k + 3) * FO + lane], acc);
        acc = fmaf(xb.x, Wp[(k + 4) * FO + lane], acc);
        acc = fmaf(xb.y, Wp[(k + 5) * FO + lane], acc);
        acc = fmaf(xb.z, Wp[(k + 6) * FO + lane], acc);
        acc = fmaf(xb.w, Wp[(k + 7) * FO + lane], acc);
    }
    part[rs][kh][lane] = acc;
    __syncthreads();
    if (threadIdx.x < 128) {
        const int r2 = threadIdx.x >> 6;
        const int l2 = threadIdx.x & 63;
        h[((size_t)blockIdx.x * 2 + r2) * FO + l2] = part[r2][0][l2] + part[r2][1][l2];
    }
}

// ---------------- K2: register-tiled e + fixed-shift p + fused PV, atomic accumulation ----------------
// Block = 256 thr = 4 waves = 64-i tile x one 128-j tile (NJT=16 j-tiles -> 512 blocks).
// e-phase: wave = 16i x 64j; lane (li=lane&3, lj=lane>>2) owns 4i x 4j.
// PV-phase: lane re-mapped to 4i x 4f through pT slice (wave-private columns; barrier
// between write and read is defensive only).
__global__ __launch_bounds__(256) void gat_attn3(const float* __restrict__ h,
                                                 const int* __restrict__ adj,
                                                 const float* __restrict__ a,
                                                 float* __restrict__ osum,
                                                 float* __restrict__ lsum) {
    __shared__ float hi_s[64 * LS];
    __shared__ float hj_s[64 * LS];
    __shared__ float pT_s[64 * PTS];
    __shared__ float a_s[FO];

    const int tid = threadIdx.x;
    const int w = tid >> 6;
    const int lane = tid & 63;
    const int li = lane & 3;
    const int lj = lane >> 2;
    const int it = blockIdx.x >> 4;          // 0..31
    const int jt = blockIdx.x & (NJT - 1);   // 0..15
    const int ib = it * 64;
    const int jb = jt * JR;
    const int iw = w * 16;

    // stage hi tile (64 x 64)
    for (int g4 = tid; g4 < 1024; g4 += 256) {
        float4 v = *(const float4*)(h + (size_t)ib * FO + (size_t)g4 * 4);
        float* d = &hi_s[(g4 >> 4) * LS + (g4 & 15) * 4];
        *(float2*)d = make_float2(v.x, v.y);
        *(float2*)(d + 2) = make_float2(v.z, v.w);
    }
    if (tid < FO) a_s[tid] = a[tid];

    float pv[4][4];
    float ls[4];
#pragma unroll
    for (int u = 0; u < 4; u++) {
        ls[u] = 0.f;
#pragma unroll
        for (int v2 = 0; v2 < 4; v2++) pv[u][v2] = 0.f;
    }

    for (int jc = 0; jc < JR; jc += 64) {
        __syncthreads();               // prev chunk fully consumed (covers hi_s/a_s on iter 0)
        const float* hsrc = h + (size_t)(jb + jc) * FO;
        for (int g4 = tid; g4 < 1024; g4 += 256) {
            float4 v = *(const float4*)(hsrc + (size_t)g4 * 4);
            float* d = &hj_s[(g4 >> 4) * LS + (g4 & 15) * 4];
            *(float2*)d = make_float2(v.x, v.y);
            *(float2*)(d + 2) = make_float2(v.z, v.w);
        }
        __syncthreads();

        // adjacency for this lane's 4x4 (16B-aligned: col offset multiple of 4 ints)
        int4 am[4];
#pragma unroll
        for (int di = 0; di < 4; di++)
            am[di] = *(const int4*)(adj + (size_t)(ib + iw + 4 * li + di) * Nn + (jb + jc + 4 * lj));

        // ---- e-phase: e[di][dj] = sum_f a_f * |hi - hj| ----
        float e[4][4];
#pragma unroll
        for (int di = 0; di < 4; di++)
#pragma unroll
            for (int dj = 0; dj < 4; dj++) e[di][dj] = 0.f;

#pragma unroll 4
        for (int f = 0; f < FO; f += 2) {
            const float2 av = *(const float2*)&a_s[f];
            float2 hi[4], hj[4];
#pragma unroll
            for (int d = 0; d < 4; d++) {
                hi[d] = *(const float2*)&hi_s[(iw + 4 * li + d) * LS + f];
                hj[d] = *(const float2*)&hj_s[(4 * lj + d) * LS + f];
            }
#pragma unroll
            for (int di = 0; di < 4; di++)
#pragma unroll
                for (int dj = 0; dj < 4; dj++) {
                    e[di][dj] = fmaf(fabsf(hi[di].x - hj[dj].x), av.x, e[di][dj]);
                    e[di][dj] = fmaf(fabsf(hi[di].y - hj[dj].y), av.y, e[di][dj]);
                }
        }

        // ---- p = adj ? exp(relu(e) - SHIFT) : 0  (shift-invariant softmax, exact) ----
#pragma unroll
        for (int di = 0; di < 4; di++) {
            const int* ap = (const int*)&am[di];
#pragma unroll
            for (int dj = 0; dj < 4; dj++) {
                const float p = (ap[dj] > 0) ? __expf(fmaxf(e[di][dj], 0.f) - SHIFT) : 0.f;
                e[di][dj] = p;
                ls[di] += p;
            }
        }

        // transpose p through pT (wave-private column slice [iw, iw+16))
#pragma unroll
        for (int dj = 0; dj < 4; dj++) {
            *(float4*)&pT_s[(4 * lj + dj) * PTS + iw + 4 * li] =
                make_float4(e[0][dj], e[1][dj], e[2][dj], e[3][dj]);
        }
        __syncthreads();   // defensive: order pT writes before PV reads explicitly

        // ---- PV: lane -> (4i x 4f): i = iw+4*li+di, f = 4*lj+v ----
#pragma unroll 4
        for (int j = 0; j < 64; j++) {
            const float4 pj = *(const float4*)&pT_s[j * PTS + iw + 4 * li];
            const float2 h0 = *(const float2*)&hj_s[j * LS + 4 * lj];
            const float2 h1 = *(const float2*)&hj_s[j * LS + 4 * lj + 2];
            pv[0][0] = fmaf(pj.x, h0.x, pv[0][0]);
            pv[0][1] = fmaf(pj.x, h0.y, pv[0][1]);
            pv[0][2] = fmaf(pj.x, h1.x, pv[0][2]);
            pv[0][3] = fmaf(pj.x, h1.y, pv[0][3]);
            pv[1][0] = fmaf(pj.y, h0.x, pv[1][0]);
            pv[1][1] = fmaf(pj.y, h0.y, pv[1][1]);
            pv[1][2] = fmaf(pj.y, h1.x, pv[1][2]);
            pv[1][3] = fmaf(pj.y, h1.y, pv[1][3]);
            pv[2][0] = fmaf(pj.z, h0.x, pv[2][0]);
            pv[2][1] = fmaf(pj.z, h0.y, pv[2][1]);
            pv[2][2] = fmaf(pj.z, h1.x, pv[2][2]);
            pv[2][3] = fmaf(pj.z, h1.y, pv[2][3]);
            pv[3][0] = fmaf(pj.w, h0.x, pv[3][0]);
            pv[3][1] = fmaf(pj.w, h0.y, pv[3][1]);
            pv[3][2] = fmaf(pj.w, h1.x, pv[3][2]);
            pv[3][3] = fmaf(pj.w, h1.y, pv[3][3]);
        }
    }

    // ---- epilogue: reduce l over lj lanes, then atomic-accumulate ----
#pragma unroll
    for (int di = 0; di < 4; di++) {
        float v = ls[di];
        v += __shfl_xor(v, 4, 64);
        v += __shfl_xor(v, 8, 64);
        v += __shfl_xor(v, 16, 64);
        v += __shfl_xor(v, 32, 64);
        ls[di] = v;
    }
    if (lj == 0) {
#pragma unroll
        for (int di = 0; di < 4; di++)
            atomicAdd(&lsum[ib + iw + 4 * li + di], ls[di]);
    }
#pragma unroll
    for (int di = 0; di < 4; di++) {
#pragma unroll
        for (int v2 = 0; v2 < 4; v2++)
            atomicAdd(&osum[(size_t)(ib + iw + 4 * li + di) * FO + 4 * lj + v2], pv[di][v2]);
    }
}

// ---------------- K3: out = relu(osum / lsum) ----------------
__global__ __launch_bounds__(256) void gat_fin(const float* __restrict__ osum,
                                               const float* __restrict__ lsum,
                                               float* __restrict__ out) {
    const int t = blockIdx.x * 256 + threadIdx.x;   // grid 512 -> 131072
    out[t] = fmaxf(osum[t] / lsum[t >> 6], 0.f);
}

extern "C" void kernel_launch(void* const* d_in, const int* in_sizes, int n_in,
                              void* d_out, int out_size, void* d_ws, size_t ws_size,
                              hipStream_t stream) {
    const float* x   = (const float*)d_in[0];
    const int*   adj = (const int*)d_in[1];
    const float* W   = (const float*)d_in[2];
    const float* a   = (const float*)d_in[3];
    float* out = (float*)d_out;

    float* h    = (float*)d_ws;                      // 131072 floats
    float* osum = h + (size_t)Nn * FO;               // 131072 floats
    float* lsum = osum + (size_t)Nn * FO;            // 2048 floats
    // total ws: 1,056,768 B — within the round-2-proven envelope

    gat_zero<<<dim3(520), dim3(256), 0, stream>>>(osum);   // zeros osum+lsum (contiguous)
    gat_xw<<<dim3(1024), dim3(256), 0, stream>>>(x, W, h);
    gat_attn3<<<dim3(32 * NJT), dim3(256), 0, stream>>>(h, adj, a, osum, lsum);
    gat_fin<<<dim3(512), dim3(256), 0, stream>>>(osum, lsum, out);
}